// Round 8
// baseline (8224.937 us; speedup 1.0000x reference)
//
#include <hip/hip_runtime.h>
#include <hip/hip_fp16.h>

// SoftRR: n=1024, m=8192, rounds=8, TAU=1.0
//   scan over 8192 rows (V tiled x8):
//     y = softmax((row - min(row) + 1) * c);  c = (1-y)*c
//   pi[i][j] = sum over rounds of y
//
// R8: multi-CU scan with single-word global sync.
// Evidence R4/R6/R7: step time ~1450 cy regardless of wave split on one CU
// (~850 cy per-SIMD issue for 8192 cols + ~600 cy serial reduce/broadcast).
// Now: 16 waves on 16 CUs (512 cols each, issue ~170 cy) synced per step by
// ONE u64: lane63 of each wave atomicAdds (1<<56)|(partial*2^20); all lanes
// spin until count byte == 16; low 56 bits are then the final fixed-point S.
// No barriers, no LDS in the scan. Sync words pre-zeroed each launch.
// Scan stores unnormalized e (fp16) + Sinv[s]; epilogue: pi = sum_r e*Sinv.

#define N_ROWS 1024
#define M_COLS 8192
#define STEPS  8192
#define LOG2E  1.4426950408889634f
#define NWAVE  16
#define FXS    1048576.0f   // 2^20 fixed-point scale

using half8  = __attribute__((ext_vector_type(8))) _Float16;
using half2v = __attribute__((ext_vector_type(2))) _Float16;
using f32x2  = __attribute__((ext_vector_type(2))) float;

__device__ __forceinline__ float fast_exp2(float x) {
#if __has_builtin(__builtin_amdgcn_exp2f)
  return __builtin_amdgcn_exp2f(x);
#else
  return exp2f(x);
#endif
}
__device__ __forceinline__ float fast_rcp(float x) {
#if __has_builtin(__builtin_amdgcn_rcpf)
  return __builtin_amdgcn_rcpf(x);
#else
  return 1.0f / x;
#endif
}
__device__ __forceinline__ half2v pack_f16(float y0, float y1) {
  return __builtin_bit_cast(half2v, __builtin_amdgcn_cvt_pkrtz(y0, y1));
}

template <int CTRL>
__device__ __forceinline__ float dpp_add(float x) {
  int yi = __builtin_amdgcn_update_dpp(0, __builtin_bit_cast(int, x),
                                       CTRL, 0xf, 0xf, true);
  return x + __builtin_bit_cast(float, yi);
}

// full 64-lane sum; result valid in lane 63
__device__ __forceinline__ float wave_sum_to_lane63(float x) {
  x = dpp_add<0x111>(x);  // row_shr:1
  x = dpp_add<0x112>(x);  // row_shr:2
  x = dpp_add<0x114>(x);  // row_shr:4
  x = dpp_add<0x118>(x);  // row_shr:8
  x = dpp_add<0x142>(x);  // row_bcast15
  x = dpp_add<0x143>(x);  // row_bcast31 -> lane63 = total
  return x;
}

// ---------------- rowmin: one block per row ----------------
__global__ void softrr_rowmin(const float* __restrict__ V, float* __restrict__ rmin) {
  const int row = blockIdx.x;
  const float* p = V + (size_t)row * M_COLS;
  float m = 1e30f;
  for (int j = threadIdx.x; j < M_COLS; j += 256) m = fminf(m, p[j]);
#pragma unroll
  for (int off = 32; off; off >>= 1) m = fminf(m, __shfl_xor(m, off, 64));
  __shared__ float sm[4];
  if ((threadIdx.x & 63) == 0) sm[threadIdx.x >> 6] = m;
  __syncthreads();
  if (threadIdx.x == 0) {
    rmin[row] = fminf(fminf(sm[0], sm[1]), fminf(sm[2], sm[3]));
  }
}

// ---------------- prep: a = (V - rowmin + 1) * log2e, fp16, canonical ----------------
__global__ void softrr_prep(const float* __restrict__ V, const float* __restrict__ rmin,
                            __half* __restrict__ A) {
  const int idx8 = blockIdx.x * 256 + threadIdx.x;   // 1M half8 groups
  const int row = idx8 >> 10;                        // 1024 half8 per row
  const float mn = rmin[row];
  const float4* v4 = (const float4*)V;
  float4 va = v4[2 * idx8];
  float4 vb = v4[2 * idx8 + 1];
  half8 o;
  o[0] = (_Float16)((va.x - mn + 1.0f) * LOG2E);
  o[1] = (_Float16)((va.y - mn + 1.0f) * LOG2E);
  o[2] = (_Float16)((va.z - mn + 1.0f) * LOG2E);
  o[3] = (_Float16)((va.w - mn + 1.0f) * LOG2E);
  o[4] = (_Float16)((vb.x - mn + 1.0f) * LOG2E);
  o[5] = (_Float16)((vb.y - mn + 1.0f) * LOG2E);
  o[6] = (_Float16)((vb.z - mn + 1.0f) * LOG2E);
  o[7] = (_Float16)((vb.w - mn + 1.0f) * LOG2E);
  ((half8*)A)[idx8] = o;
}

// ---------------- zero the sync words ----------------
__global__ void softrr_zero(unsigned long long* __restrict__ Sync) {
  Sync[blockIdx.x * 256 + threadIdx.x] = 0ULL;
}

// ---------------- main scan: 16 WGs x 64 thr, global single-word sync ----------------
__global__ void __launch_bounds__(64) softrr_scan_g(const __half* __restrict__ Ah,
                                                    __half* __restrict__ Eh,
                                                    float* __restrict__ SinvW,
                                                    unsigned long long* __restrict__ Sync) {
  const int w    = blockIdx.x;        // 0..15, owns cols 512w..512w+511
  const int lane = threadIdx.x;       // 0..63
  const int base = 64 * w + lane;     // half8 index within a row

  const half8* __restrict__ A8 = (const half8*)Ah;
  half8* __restrict__ E8 = (half8*)Eh;

  f32x2 c[4];
#pragma unroll
  for (int k = 0; k < 4; ++k) c[k] = (f32x2){1.0f, 1.0f};

  half8 X = A8[base];            // row 0
  half8 Y = A8[1024 + base];     // row 1

  auto half_step = [&](half8& B, int s) {
    // e = exp2(a*c)
    f32x2 e[4];
#pragma unroll
    for (int j = 0; j < 4; ++j) {
      e[j][0] = fast_exp2((float)B[2 * j]     * c[j][0]);
      e[j][1] = fast_exp2((float)B[2 * j + 1] * c[j][1]);
    }
    // prefetch row s+2 into the just-consumed buffer
    B = A8[((s + 2) & (N_ROWS - 1)) * 1024 + base];

    // pack + store unnormalized e
    half8 o;
#pragma unroll
    for (int j = 0; j < 4; ++j) {
      half2v h = pack_f16(e[j][0], e[j][1]);
      o[2 * j] = h[0]; o[2 * j + 1] = h[1];
    }
    E8[(size_t)s * 1024 + base] = o;

    // wave-local sum
    f32x2 u = (e[0] + e[1]) + (e[2] + e[3]);
    float l = u[0] + u[1];
    l = wave_sum_to_lane63(l);

    // global single-word protocol: count in top byte, 2^20 fixed-point sum below
    if (lane == 63) {
      unsigned long long pk = (1ULL << 56) | (unsigned long long)(l * FXS);
      __hip_atomic_fetch_add(&Sync[s], pk, __ATOMIC_RELAXED, __HIP_MEMORY_SCOPE_AGENT);
    }
    unsigned long long v;
    do {
      v = __hip_atomic_load(&Sync[s], __ATOMIC_RELAXED, __HIP_MEMORY_SCOPE_AGENT);
    } while ((v >> 56) != (unsigned long long)NWAVE);

    const float S = (float)(v & 0x00FFFFFFFFFFFFFFULL) * (1.0f / FXS);
    const float Sinv = fast_rcp(S);
    if (w == 0 && lane == 0) SinvW[s] = Sinv;

    const f32x2 Sv = (f32x2){Sinv, Sinv};
#pragma unroll
    for (int j = 0; j < 4; ++j) {
      e[j] = c[j] * e[j];        // ce
      c[j] = c[j] - e[j] * Sv;   // c -= ce*Sinv
    }
  };

  for (int s = 0; s < STEPS; s += 2) {
    half_step(X, s);
    half_step(Y, s + 1);
  }
}

// ---------------- epilogue: out = sum_r E[r*1024+i] * Sinv[r*1024+i] ----------------
__global__ void softrr_sum8s(const __half* __restrict__ Eh,
                             const float* __restrict__ SinvW,
                             float* __restrict__ out) {
  const int idx8 = blockIdx.x * 256 + threadIdx.x;   // 1M half8 outputs
  const int i = idx8 >> 10;                          // output row
  const int w = idx8 & 1023;                         // half8 within row
  const half8* E8 = (const half8*)Eh;

  float si[8];
#pragma unroll
  for (int r = 0; r < 8; ++r) si[r] = SinvW[r * 1024 + i];

  float acc[8];
#pragma unroll
  for (int k = 0; k < 8; ++k) acc[k] = 0.0f;
#pragma unroll
  for (int r = 0; r < 8; ++r) {
    half8 v = E8[(size_t)(r * 1024 + i) * 1024 + w];
#pragma unroll
    for (int k = 0; k < 8; ++k) acc[k] = __builtin_fmaf((float)v[k], si[r], acc[k]);
  }
  ((float4*)out)[2 * idx8]     = make_float4(acc[0], acc[1], acc[2], acc[3]);
  ((float4*)out)[2 * idx8 + 1] = make_float4(acc[4], acc[5], acc[6], acc[7]);
}

// ---------------- fallback: f32 direct (tiny ws) ----------------
__global__ void __launch_bounds__(1024) softrr_scan_b(const float* __restrict__ V,
                                                      const float* __restrict__ rmin,
                                                      float* __restrict__ out) {
  const int t = threadIdx.x;
  const int wave = t >> 6;
  const int lane = t & 63;
  __shared__ float partials[2][16];
  __shared__ float smin[N_ROWS];
  smin[t] = rmin[t];
  __syncthreads();
  const float4* __restrict__ V4 = (const float4*)V;
  float4* O4 = (float4*)out;
  float c[8];
#pragma unroll
  for (int k = 0; k < 8; ++k) c[k] = 1.0f;
  float4 va = V4[2 * t], vb = V4[2 * t + 1];
  float4 pa, pb;
  for (int s = 0; s < STEPS; ++s) {
    const int i = s & (N_ROWS - 1);
    const int r = s >> 10;
    const int in_ = (s + 1) & (N_ROWS - 1);
    float4 van = V4[in_ * 2048 + 2 * t];
    float4 vbn = V4[in_ * 2048 + 2 * t + 1];
    const float mn = smin[i];
    const float base = (1.0f - mn) * LOG2E;
    float vv[8] = {va.x, va.y, va.z, va.w, vb.x, vb.y, vb.z, vb.w};
    float e[8];
    float l = 0.0f;
#pragma unroll
    for (int k = 0; k < 8; ++k) {
      float zb = __builtin_fmaf(vv[k], LOG2E, base);
      e[k] = fast_exp2(zb * c[k]);
      l += e[k];
    }
#pragma unroll
    for (int off = 32; off; off >>= 1) l += __shfl_xor(l, off, 64);
    if (lane == 0) partials[s & 1][wave] = l;
    __syncthreads();
    float S = 0.0f;
#pragma unroll
    for (int ww = 0; ww < 16; ++ww) S += partials[s & 1][ww];
    const float Sinv = fast_rcp(S);
    float po[8] = {pa.x, pa.y, pa.z, pa.w, pb.x, pb.y, pb.z, pb.w};
    float o[8];
#pragma unroll
    for (int k = 0; k < 8; ++k) {
      float y = e[k] * Sinv;
      c[k] = __builtin_fmaf(-y, c[k], c[k]);
      o[k] = (r > 0) ? (po[k] + y) : y;
    }
    O4[i * 2048 + 2 * t]     = make_float4(o[0], o[1], o[2], o[3]);
    O4[i * 2048 + 2 * t + 1] = make_float4(o[4], o[5], o[6], o[7]);
    va = van; vb = vbn;
    pa = O4[in_ * 2048 + 2 * t];
    pb = O4[in_ * 2048 + 2 * t + 1];
  }
}

extern "C" void kernel_launch(void* const* d_in, const int* in_sizes, int n_in,
                              void* d_out, int out_size, void* d_ws, size_t ws_size,
                              hipStream_t stream) {
  const float* V = (const float*)d_in[0];
  float* out = (float*)d_out;
  float* rmin = (float*)d_ws;

  const size_t E_BYTES  = (size_t)STEPS * M_COLS * 2;   // 128 MiB
  const size_t S_BYTES  = (size_t)STEPS * 4;            // 32 KiB
  const size_t SY_BYTES = (size_t)STEPS * 8;            // 64 KiB
  const size_t need = 4096 + E_BYTES + S_BYTES + SY_BYTES;

  if (ws_size >= need) {
    // A (fp16, 16 MiB) lives in d_out's first half; epilogue overwrites d_out.
    __half* A    = (__half*)out;
    __half* E    = (__half*)((char*)d_ws + 4096);
    float*  Sinv = (float*)((char*)d_ws + 4096 + E_BYTES);
    unsigned long long* Sync =
        (unsigned long long*)((char*)d_ws + 4096 + E_BYTES + S_BYTES);
    softrr_rowmin<<<N_ROWS, 256, 0, stream>>>(V, rmin);
    softrr_prep<<<4096, 256, 0, stream>>>(V, rmin, A);
    softrr_zero<<<STEPS / 256, 256, 0, stream>>>(Sync);
    softrr_scan_g<<<NWAVE, 64, 0, stream>>>(A, E, Sinv, Sync);
    softrr_sum8s<<<4096, 256, 0, stream>>>(E, Sinv, out);
  } else {
    softrr_rowmin<<<N_ROWS, 256, 0, stream>>>(V, rmin);
    softrr_scan_b<<<1, 1024, 0, stream>>>(V, rmin, out);
  }
}

// Round 9
// 5856.406 us; speedup vs baseline: 1.4044x; 1.4044x over previous
//
#include <hip/hip_runtime.h>
#include <hip/hip_fp16.h>

// SoftRR: n=1024, m=8192, rounds=8, TAU=1.0
//   scan over 8192 rows (V tiled x8):
//     y = softmax((row - min(row) + 1) * c);  c = (1-y)*c
//   pi[i][j] = sum over rounds of y
//
// R9: single-CU scan (4 waves, 32 cols/thread) with the per-step barrier
// replaced by an LDS atomic turnstile: lane63 of each wave ds_add_u64's
// (1<<56)|(partial*2^20) into one LDS slot; all lanes spin on ds_read_b64
// until count byte == 4. No s_barrier in the loop; serial phase drops from
// ~590cy (DPP+ds_write+barrier+ds_read+rcp) to ~350cy (DPP+ds_add+poll+rcp).
// 4-deep slot rotation; wave0 pre-resets slot (s+2) each step (safe: any
// wave at step s implies all waves consumed slot s-2; no wave can reach
// step s+2's add before wave0's add for s+1, which follows the reset).
// Evidence: R8 showed cross-CU sync costs ~2200cy (L3 round trips) — dead;
// R4/R6/R7 all ~1450cy/step regardless of wave split -> serial phase is the
// only attackable term on one CU.
// Scan stores unnormalized e (fp16) + Sinv[s]; epilogue: pi = sum_r e*Sinv.

#define N_ROWS 1024
#define M_COLS 8192
#define STEPS  8192
#define LOG2E  1.4426950408889634f
#define FXS    1048576.0f   // 2^20 fixed-point scale

using half8  = __attribute__((ext_vector_type(8))) _Float16;
using half2v = __attribute__((ext_vector_type(2))) _Float16;
using f32x2  = __attribute__((ext_vector_type(2))) float;

__device__ __forceinline__ float fast_exp2(float x) {
#if __has_builtin(__builtin_amdgcn_exp2f)
  return __builtin_amdgcn_exp2f(x);
#else
  return exp2f(x);
#endif
}
__device__ __forceinline__ float fast_rcp(float x) {
#if __has_builtin(__builtin_amdgcn_rcpf)
  return __builtin_amdgcn_rcpf(x);
#else
  return 1.0f / x;
#endif
}
__device__ __forceinline__ half2v pack_f16(float y0, float y1) {
  return __builtin_bit_cast(half2v, __builtin_amdgcn_cvt_pkrtz(y0, y1));
}

template <int CTRL>
__device__ __forceinline__ float dpp_add(float x) {
  int yi = __builtin_amdgcn_update_dpp(0, __builtin_bit_cast(int, x),
                                       CTRL, 0xf, 0xf, true);
  return x + __builtin_bit_cast(float, yi);
}

// full 64-lane sum; result valid in lane 63
__device__ __forceinline__ float wave_sum_to_lane63(float x) {
  x = dpp_add<0x111>(x);  // row_shr:1
  x = dpp_add<0x112>(x);  // row_shr:2
  x = dpp_add<0x114>(x);  // row_shr:4
  x = dpp_add<0x118>(x);  // row_shr:8
  x = dpp_add<0x142>(x);  // row_bcast15
  x = dpp_add<0x143>(x);  // row_bcast31 -> lane63 = total
  return x;
}

// ---------------- rowmin: one block per row ----------------
__global__ void softrr_rowmin(const float* __restrict__ V, float* __restrict__ rmin) {
  const int row = blockIdx.x;
  const float* p = V + (size_t)row * M_COLS;
  float m = 1e30f;
  for (int j = threadIdx.x; j < M_COLS; j += 256) m = fminf(m, p[j]);
#pragma unroll
  for (int off = 32; off; off >>= 1) m = fminf(m, __shfl_xor(m, off, 64));
  __shared__ float sm[4];
  if ((threadIdx.x & 63) == 0) sm[threadIdx.x >> 6] = m;
  __syncthreads();
  if (threadIdx.x == 0) {
    rmin[row] = fminf(fminf(sm[0], sm[1]), fminf(sm[2], sm[3]));
  }
}

// ---------------- prep: a = (V - rowmin + 1)*log2e, fp16, PERMUTED ----------------
// Perm: half8-chunk (q,t) of a row sits at perm index q*256+t and holds
// canonical cols 8*(4t+q)..+7.  (q in [0,4), t in [0,256))
__global__ void softrr_prep_perm(const float* __restrict__ V, const float* __restrict__ rmin,
                                 __half* __restrict__ A) {
  const int gid = blockIdx.x * 256 + threadIdx.x;   // 1M perm half8 chunks
  const int row = gid >> 10;
  const int pc  = gid & 1023;
  const int q   = pc >> 8;
  const int tt  = pc & 255;
  const int cc  = 4 * tt + q;                       // canonical half8 chunk
  const float mn = rmin[row];
  const float4* V4 = (const float4*)V;
  float4 va = V4[row * 2048 + 2 * cc];
  float4 vb = V4[row * 2048 + 2 * cc + 1];
  half8 o;
  o[0] = (_Float16)((va.x - mn + 1.0f) * LOG2E);
  o[1] = (_Float16)((va.y - mn + 1.0f) * LOG2E);
  o[2] = (_Float16)((va.z - mn + 1.0f) * LOG2E);
  o[3] = (_Float16)((va.w - mn + 1.0f) * LOG2E);
  o[4] = (_Float16)((vb.x - mn + 1.0f) * LOG2E);
  o[5] = (_Float16)((vb.y - mn + 1.0f) * LOG2E);
  o[6] = (_Float16)((vb.z - mn + 1.0f) * LOG2E);
  o[7] = (_Float16)((vb.w - mn + 1.0f) * LOG2E);
  ((half8*)A)[gid] = o;
}

// ---------------- main scan: 256 thr (4 waves), LDS atomic turnstile ----------------
__global__ void __launch_bounds__(256) softrr_scan_t(const __half* __restrict__ Ah,
                                                     __half* __restrict__ Eh,
                                                     float* __restrict__ SinvW) {
  const int t = threadIdx.x;        // 0..255
  const int wave = t >> 6;          // 0..3
  const int lane = t & 63;
  __shared__ unsigned long long slot[4];   // 4-deep rotation

  if (t < 4) slot[t] = 0ULL;
  __syncthreads();                          // one-time init barrier only

  const half8* __restrict__ A8 = (const half8*)Ah;
  half8* __restrict__ E8 = (half8*)Eh;

  f32x2 c[16];
#pragma unroll
  for (int k = 0; k < 16; ++k) c[k] = (f32x2){1.0f, 1.0f};

  half8 X[4], Y[4];                 // even/odd row buffers
#pragma unroll
  for (int q = 0; q < 4; ++q) X[q] = A8[q * 256 + t];
#pragma unroll
  for (int q = 0; q < 4; ++q) Y[q] = A8[1024 + q * 256 + t];

  unsigned aoffE = 2 * 1024, aoffO = 3 * 1024;   // perm half8 index of prefetch row
  unsigned eoffE = 0,        eoffO = 1024;       // perm half8 index of E row

  auto half_step = [&](half8 (&B)[4], unsigned aoff, unsigned eoff, int s) {
    // wave0 lane63: pre-reset the slot step s+2 will use (holds consumed s-2)
    if (wave == 0 && lane == 63) {
      __hip_atomic_store(&slot[(s + 2) & 3], 0ULL,
                         __ATOMIC_RELAXED, __HIP_MEMORY_SCOPE_WORKGROUP);
    }

    // e = exp2(a*c)
    f32x2 e[16];
#pragma unroll
    for (int q = 0; q < 4; ++q) {
#pragma unroll
      for (int j = 0; j < 4; ++j) {
        const int k = q * 4 + j;
        e[k][0] = fast_exp2((float)B[q][2 * j]     * c[k][0]);
        e[k][1] = fast_exp2((float)B[q][2 * j + 1] * c[k][1]);
      }
    }
    // prefetch row s+2 into the just-freed buffer
#pragma unroll
    for (int q = 0; q < 4; ++q) B[q] = A8[aoff + q * 256 + t];

    // pack + store unnormalized e (pre-sync)
#pragma unroll
    for (int q = 0; q < 4; ++q) {
      half8 o;
#pragma unroll
      for (int j = 0; j < 4; ++j) {
        half2v h = pack_f16(e[q * 4 + j][0], e[q * 4 + j][1]);
        o[2 * j] = h[0]; o[2 * j + 1] = h[1];
      }
      E8[eoff + q * 256 + t] = o;
    }

    // packed tree sum -> scalar
    f32x2 u0 = (e[0] + e[1]) + (e[2] + e[3]);
    f32x2 u1 = (e[4] + e[5]) + (e[6] + e[7]);
    f32x2 u2 = (e[8] + e[9]) + (e[10] + e[11]);
    f32x2 u3 = (e[12] + e[13]) + (e[14] + e[15]);
    f32x2 tw = (u0 + u1) + (u2 + u3);
    float l = tw[0] + tw[1];
    l = wave_sum_to_lane63(l);

    // turnstile: count in top byte, 2^20 fixed-point sum below (exact add)
    if (lane == 63) {
      unsigned long long pk = (1ULL << 56) | (unsigned long long)(l * FXS);
      __hip_atomic_fetch_add(&slot[s & 3], pk,
                             __ATOMIC_RELAXED, __HIP_MEMORY_SCOPE_WORKGROUP);
    }
    unsigned long long v;
    do {
      v = __hip_atomic_load(&slot[s & 3],
                            __ATOMIC_RELAXED, __HIP_MEMORY_SCOPE_WORKGROUP);
    } while ((v >> 56) != 4ULL);

    const unsigned lo = (unsigned)v;
    const unsigned hi = (unsigned)(v >> 32) & 0x00FFFFFFu;
    const float S = (float)lo * (1.0f / FXS) + (float)hi * 4096.0f;  // 2^32/2^20
    const float Sinv = fast_rcp(S);
    if (t == 0) SinvW[s] = Sinv;

    // ce overwrites e, then c -= ce*Sinv  (v_pk_mul / v_pk_fma)
    const f32x2 Sv = (f32x2){Sinv, Sinv};
#pragma unroll
    for (int k = 0; k < 16; ++k) {
      e[k] = c[k] * e[k];
      c[k] = c[k] - e[k] * Sv;
    }
  };

  for (int s = 0; s < STEPS; s += 2) {
    half_step(X, aoffE, eoffE, s);
    aoffE = (aoffE + 2048) & (1024 * 1024 - 1);
    eoffE += 2048;
    half_step(Y, aoffO, eoffO, s + 1);
    aoffO = (aoffO + 2048) & (1024 * 1024 - 1);
    eoffO += 2048;
  }
}

// ---------------- epilogue: out = sum_r E_perm * Sinv, de-permute ----------------
__global__ void softrr_sum8p(const __half* __restrict__ Eh,
                             const float* __restrict__ SinvW,
                             float* __restrict__ out) {
  const int gid = blockIdx.x * 256 + threadIdx.x;   // 1M perm half8 chunks
  const int i  = gid >> 10;                         // output row
  const int pc = gid & 1023;
  const int q  = pc >> 8;
  const int tt = pc & 255;
  const int cc = 4 * tt + q;                        // canonical half8 chunk
  const half8* E8 = (const half8*)Eh;

  float si[8];
#pragma unroll
  for (int r = 0; r < 8; ++r) si[r] = SinvW[r * 1024 + i];

  float acc[8];
#pragma unroll
  for (int k = 0; k < 8; ++k) acc[k] = 0.0f;
#pragma unroll
  for (int r = 0; r < 8; ++r) {
    half8 v = E8[(size_t)(r * 1024 + i) * 1024 + pc];
#pragma unroll
    for (int k = 0; k < 8; ++k) acc[k] = __builtin_fmaf((float)v[k], si[r], acc[k]);
  }
  ((float4*)out)[(size_t)i * 2048 + 2 * cc]     = make_float4(acc[0], acc[1], acc[2], acc[3]);
  ((float4*)out)[(size_t)i * 2048 + 2 * cc + 1] = make_float4(acc[4], acc[5], acc[6], acc[7]);
}

// ---------------- fallback: f32 direct (tiny ws) ----------------
__global__ void __launch_bounds__(1024) softrr_scan_b(const float* __restrict__ V,
                                                      const float* __restrict__ rmin,
                                                      float* __restrict__ out) {
  const int t = threadIdx.x;
  const int wave = t >> 6;
  const int lane = t & 63;
  __shared__ float partials[2][16];
  __shared__ float smin[N_ROWS];
  smin[t] = rmin[t];
  __syncthreads();
  const float4* __restrict__ V4 = (const float4*)V;
  float4* O4 = (float4*)out;
  float c[8];
#pragma unroll
  for (int k = 0; k < 8; ++k) c[k] = 1.0f;
  float4 va = V4[2 * t], vb = V4[2 * t + 1];
  float4 pa, pb;
  for (int s = 0; s < STEPS; ++s) {
    const int i = s & (N_ROWS - 1);
    const int r = s >> 10;
    const int in_ = (s + 1) & (N_ROWS - 1);
    float4 van = V4[in_ * 2048 + 2 * t];
    float4 vbn = V4[in_ * 2048 + 2 * t + 1];
    const float mn = smin[i];
    const float base = (1.0f - mn) * LOG2E;
    float vv[8] = {va.x, va.y, va.z, va.w, vb.x, vb.y, vb.z, vb.w};
    float e[8];
    float l = 0.0f;
#pragma unroll
    for (int k = 0; k < 8; ++k) {
      float zb = __builtin_fmaf(vv[k], LOG2E, base);
      e[k] = fast_exp2(zb * c[k]);
      l += e[k];
    }
#pragma unroll
    for (int off = 32; off; off >>= 1) l += __shfl_xor(l, off, 64);
    if (lane == 0) partials[s & 1][wave] = l;
    __syncthreads();
    float S = 0.0f;
#pragma unroll
    for (int ww = 0; ww < 16; ++ww) S += partials[s & 1][ww];
    const float Sinv = fast_rcp(S);
    float po[8] = {pa.x, pa.y, pa.z, pa.w, pb.x, pb.y, pb.z, pb.w};
    float o[8];
#pragma unroll
    for (int k = 0; k < 8; ++k) {
      float y = e[k] * Sinv;
      c[k] = __builtin_fmaf(-y, c[k], c[k]);
      o[k] = (r > 0) ? (po[k] + y) : y;
    }
    O4[i * 2048 + 2 * t]     = make_float4(o[0], o[1], o[2], o[3]);
    O4[i * 2048 + 2 * t + 1] = make_float4(o[4], o[5], o[6], o[7]);
    va = van; vb = vbn;
    pa = O4[in_ * 2048 + 2 * t];
    pb = O4[in_ * 2048 + 2 * t + 1];
  }
}

extern "C" void kernel_launch(void* const* d_in, const int* in_sizes, int n_in,
                              void* d_out, int out_size, void* d_ws, size_t ws_size,
                              hipStream_t stream) {
  const float* V = (const float*)d_in[0];
  float* out = (float*)d_out;
  float* rmin = (float*)d_ws;

  const size_t E_BYTES = (size_t)STEPS * M_COLS * 2;   // 128 MiB
  const size_t S_BYTES = (size_t)STEPS * 4;            // 32 KiB
  const size_t need = 4096 + E_BYTES + S_BYTES;

  if (ws_size >= need) {
    // A (fp16 perm, 16 MiB) lives in d_out's first half; epilogue overwrites d_out.
    __half* A    = (__half*)out;
    __half* E    = (__half*)((char*)d_ws + 4096);
    float*  Sinv = (float*)((char*)d_ws + 4096 + E_BYTES);
    softrr_rowmin<<<N_ROWS, 256, 0, stream>>>(V, rmin);
    softrr_prep_perm<<<4096, 256, 0, stream>>>(V, rmin, A);
    softrr_scan_t<<<1, 256, 0, stream>>>(A, E, Sinv);
    softrr_sum8p<<<4096, 256, 0, stream>>>(E, Sinv, out);
  } else {
    softrr_rowmin<<<N_ROWS, 256, 0, stream>>>(V, rmin);
    softrr_scan_b<<<1, 1024, 0, stream>>>(V, rmin, out);
  }
}